// Round 1
// baseline (2614.442 us; speedup 1.0000x reference)
//
#include <hip/hip_runtime.h>
#include <hip/hip_bf16.h>
#include <math.h>

// ---------------- problem constants ----------------
#define S_LEN 2048
#define NHEAD 16
#define DQ_   192      // DN(128) + DR(64)
#define DV_   128
#define QCOLS (NHEAD * DQ_)   // 3072
#define VCOLS (NHEAD * DV_)   // 2048
#define QR_   1536
#define KVR_  512
#define H_    2048
#define ATT_SCALE 0.07216878364870323f   // 1/sqrt(192)

// =====================================================================
// Generic tiled fp32 GEMM: C = A(MxK) @ B(KxN), all row-major.
// 256 threads; per-thread micro-tile WM x WN; K-step 16.
// =====================================================================
template<int TM, int TN, int WM, int WN>
__global__ __launch_bounds__(256) void gemm_f32(
    const float* __restrict__ A, const float* __restrict__ B,
    float* __restrict__ C, int M, int N, int K)
{
    constexpr int TK  = 16;
    constexpr int NTX = TN / WN;                 // threads along n
    constexpr int ALD = TM * TK / (4 * 256);     // float4 A-loads per thread
    constexpr int BLD = TK * TN / (4 * 256);     // float4 B-loads per thread
    static_assert((TM / WM) * (TN / WN) == 256, "thread count");

    __shared__ float As[TK][TM];   // transposed: As[k][m]
    __shared__ float Bs[TK][TN];   // natural:    Bs[k][n]

    const int t  = threadIdx.x;
    const int tx = t % NTX;
    const int ty = t / NTX;
    const long bm = (long)blockIdx.y * TM;
    const long bn = (long)blockIdx.x * TN;

    float acc[WM][WN];
#pragma unroll
    for (int i = 0; i < WM; ++i)
#pragma unroll
        for (int j = 0; j < WN; ++j) acc[i][j] = 0.f;

    for (int k0 = 0; k0 < K; k0 += TK) {
        float4 ar[ALD], br[BLD];
#pragma unroll
        for (int l = 0; l < ALD; ++l) {
            int idx = t + l * 256;
            int row = idx / (TK / 4);
            int kc  = (idx % (TK / 4)) * 4;
            ar[l] = *(const float4*)&A[(bm + row) * K + (k0 + kc)];
        }
#pragma unroll
        for (int l = 0; l < BLD; ++l) {
            int idx = t + l * 256;
            int kr  = idx / (TN / 4);
            int nc  = (idx % (TN / 4)) * 4;
            br[l] = *(const float4*)&B[(long)(k0 + kr) * N + bn + nc];
        }
        __syncthreads();   // previous iter's LDS reads done
#pragma unroll
        for (int l = 0; l < ALD; ++l) {
            int idx = t + l * 256;
            int row = idx / (TK / 4);
            int kc  = (idx % (TK / 4)) * 4;
            As[kc + 0][row] = ar[l].x;
            As[kc + 1][row] = ar[l].y;
            As[kc + 2][row] = ar[l].z;
            As[kc + 3][row] = ar[l].w;
        }
#pragma unroll
        for (int l = 0; l < BLD; ++l) {
            int idx = t + l * 256;
            int kr  = idx / (TN / 4);
            int nc  = (idx % (TN / 4)) * 4;
            *(float4*)&Bs[kr][nc] = br[l];
        }
        __syncthreads();
#pragma unroll
        for (int kk = 0; kk < TK; ++kk) {
            float av[WM], bv[WN];
#pragma unroll
            for (int i = 0; i < WM; i += 4)
                *(float4*)&av[i] = *(float4*)&As[kk][ty * WM + i];
#pragma unroll
            for (int j = 0; j < WN; j += 4)
                *(float4*)&bv[j] = *(float4*)&Bs[kk][tx * WN + j];
#pragma unroll
            for (int i = 0; i < WM; ++i)
#pragma unroll
                for (int j = 0; j < WN; ++j)
                    acc[i][j] = fmaf(av[i], bv[j], acc[i][j]);
        }
    }
#pragma unroll
    for (int i = 0; i < WM; ++i) {
        long r = bm + ty * WM + i;
#pragma unroll
        for (int j = 0; j < WN; j += 4) {
            float4 o;
            o.x = acc[i][j]; o.y = acc[i][j + 1];
            o.z = acc[i][j + 2]; o.w = acc[i][j + 3];
            *(float4*)&C[r * N + bn + tx * WN + j] = o;
        }
    }
}

// =====================================================================
// RMSNorm in-place over rows of x (one block per row).
// =====================================================================
__global__ __launch_bounds__(256) void rmsnorm_k(
    float* __restrict__ x, const float* __restrict__ w, int N, float invN)
{
    const int row = blockIdx.x;
    float* xr = x + (long)row * N;
    const int t = threadIdx.x;

    float ss = 0.f;
    for (int i = t * 4; i < N; i += 1024) {
        float4 v = *(float4*)&xr[i];
        ss += v.x * v.x + v.y * v.y + v.z * v.z + v.w * v.w;
    }
#pragma unroll
    for (int off = 32; off > 0; off >>= 1) ss += __shfl_down(ss, off, 64);

    __shared__ float red[4];
    __shared__ float sinv;
    if ((t & 63) == 0) red[t >> 6] = ss;
    __syncthreads();
    if (t == 0) {
        float tot = red[0] + red[1] + red[2] + red[3];
        sinv = 1.f / sqrtf(tot * invN + 1e-5f);
    }
    __syncthreads();
    const float si = sinv;
    for (int i = t * 4; i < N; i += 1024) {
        float4 v  = *(float4*)&xr[i];
        float4 wv = *(const float4*)&w[i];
        v.x *= wv.x * si; v.y *= wv.y * si;
        v.z *= wv.z * si; v.w *= wv.w * si;
        *(float4*)&xr[i] = v;
    }
}

// =====================================================================
// RoPE cos/sin table: [S][32] each (freqs repeat for dims 32..63).
// =====================================================================
__global__ __launch_bounds__(256) void rope_table_k(
    float* __restrict__ cost, float* __restrict__ sint)
{
    int idx = blockIdx.x * 256 + threadIdx.x;     // S*32 total
    int tp = idx >> 5, j = idx & 31;
    float invf = powf(100000.0f, -(float)j * (1.0f / 32.0f));
    float fr = (float)tp * invf;
    cost[idx] = cosf(fr);
    sint[idx] = sinf(fr);
}

// Apply RoPE in-place to last 64 cols of each head in a (S, NH*192) tensor.
__global__ __launch_bounds__(256) void rope_apply_k(
    float* __restrict__ qk, const float* __restrict__ cost,
    const float* __restrict__ sint)
{
    int idx = blockIdx.x * 256 + threadIdx.x;     // S*NH*32 total
    int j = idx & 31;
    int h = (idx >> 5) & 15;
    int s = idx >> 9;
    float* p = qk + (long)s * QCOLS + h * DQ_ + 128;
    float a = p[j], b = p[j + 32];
    float c  = cost[(s << 5) + j];
    float sn = sint[(s << 5) + j];
    p[j]      = fmaf(a, c, -b * sn);
    p[j + 32] = fmaf(b, c,  a * sn);
}

// =====================================================================
// Flash-style causal attention, fp32.
// grid: (S/64, NH); 256 threads. QB=KB=64 tiles.
// K tile XOR-swizzled on float4 index by (row>>2)&7 to kill the 16-way
// bank conflict in the score phase (row stride 192 floats = 0 mod 32 banks).
// P tile padded to 65 cols for the softmax column scan.
// =====================================================================
#define QB 64
#define KB 64

__global__ __launch_bounds__(256) void attn_k(
    const float* __restrict__ q, const float* __restrict__ k,
    const float* __restrict__ v, float* __restrict__ o)
{
    const int h  = blockIdx.y;
    const int qt = blockIdx.x;
    const int qbase = qt * QB;

    __shared__ float Qs[QB][DQ_];       // 48 KB
    __shared__ float Ks[KB][DQ_];       // 48 KB (swizzled)
    __shared__ float Vs[KB][DV_];       // 32 KB
    __shared__ float Ps[QB][KB + 1];    // 16.25 KB
    __shared__ float mrow[QB], lrow[QB], crow[QB];

    const int t = threadIdx.x;

    // load Q tile (rows broadcast-read later; no swizzle needed)
    for (int i = t; i < QB * 48; i += 256) {
        int r = i / 48, c4 = i % 48;
        *(float4*)&Qs[r][c4 * 4] =
            *(const float4*)&q[(long)(qbase + r) * QCOLS + h * DQ_ + c4 * 4];
    }
    if (t < QB) { mrow[t] = -1e30f; lrow[t] = 0.f; }

    float O[4][8];
#pragma unroll
    for (int i = 0; i < 4; ++i)
#pragma unroll
        for (int j = 0; j < 8; ++j) O[i][j] = 0.f;

    const int orow = (t >> 4) * 4;     // 4 q-rows owned (PV phase)
    const int odv  = (t & 15) * 8;     // 8 v-cols owned
    const int sr   = (t >> 4) * 4;     // score rows
    const int sc   = (t & 15) * 4;     // score cols

    for (int kt = 0; kt <= qt; ++kt) {
        const int kbase = kt * KB;
        __syncthreads();               // previous tile fully consumed
        // stage K (swizzled) and V
        for (int i = t; i < KB * 48; i += 256) {
            int r = i / 48, c4 = i % 48;
            int c4s = c4 ^ ((r >> 2) & 7);
            *(float4*)&Ks[r][c4s * 4] =
                *(const float4*)&k[(long)(kbase + r) * QCOLS + h * DQ_ + c4 * 4];
        }
        for (int i = t; i < KB * 32; i += 256) {
            int r = i / 32, c4 = i % 32;
            *(float4*)&Vs[r][c4 * 4] =
                *(const float4*)&v[(long)(kbase + r) * VCOLS + h * DV_ + c4 * 4];
        }
        __syncthreads();

        // ---- scores: 4x4 per thread over d=192 ----
        float s4[4][4];
#pragma unroll
        for (int i = 0; i < 4; ++i)
#pragma unroll
            for (int j = 0; j < 4; ++j) s4[i][j] = 0.f;

        for (int d4 = 0; d4 < 48; ++d4) {
            float4 qv[4], kv[4];
#pragma unroll
            for (int i = 0; i < 4; ++i)
                qv[i] = *(float4*)&Qs[sr + i][d4 * 4];
#pragma unroll
            for (int j = 0; j < 4; ++j) {
                int c4s = d4 ^ (((sc + j) >> 2) & 7);
                kv[j] = *(float4*)&Ks[sc + j][c4s * 4];
            }
#pragma unroll
            for (int i = 0; i < 4; ++i)
#pragma unroll
                for (int j = 0; j < 4; ++j)
                    s4[i][j] += qv[i].x * kv[j].x + qv[i].y * kv[j].y
                              + qv[i].z * kv[j].z + qv[i].w * kv[j].w;
        }
#pragma unroll
        for (int i = 0; i < 4; ++i) {
            int qg = qbase + sr + i;
#pragma unroll
            for (int j = 0; j < 4; ++j) {
                int kg = kbase + sc + j;
                Ps[sr + i][sc + j] = (kg <= qg) ? s4[i][j] * ATT_SCALE : -1e30f;
            }
        }
        __syncthreads();

        // ---- online softmax (one thread per q-row; wave 0) ----
        if (t < QB) {
            float mo = mrow[t];
            float mx = mo;
            for (int j = 0; j < KB; ++j) mx = fmaxf(mx, Ps[t][j]);
            float c = expf(mo - mx);
            float ssum = 0.f;
            for (int j = 0; j < KB; ++j) {
                float p = expf(Ps[t][j] - mx);
                Ps[t][j] = p;
                ssum += p;
            }
            lrow[t] = lrow[t] * c + ssum;
            mrow[t] = mx;
            crow[t] = c;
        }
        __syncthreads();

        // ---- rescale + PV ----
        float cc[4];
#pragma unroll
        for (int i = 0; i < 4; ++i) cc[i] = crow[orow + i];
#pragma unroll
        for (int i = 0; i < 4; ++i)
#pragma unroll
            for (int j = 0; j < 8; ++j) O[i][j] *= cc[i];

        for (int j = 0; j < KB; ++j) {
            float4 v0 = *(float4*)&Vs[j][odv];
            float4 v1 = *(float4*)&Vs[j][odv + 4];
            float vv[8];
            *(float4*)&vv[0] = v0;
            *(float4*)&vv[4] = v1;
            float pr[4] = { Ps[orow + 0][j], Ps[orow + 1][j],
                            Ps[orow + 2][j], Ps[orow + 3][j] };
#pragma unroll
            for (int i = 0; i < 4; ++i)
#pragma unroll
                for (int jj = 0; jj < 8; ++jj)
                    O[i][jj] = fmaf(pr[i], vv[jj], O[i][jj]);
        }
    }

    // ---- epilogue: normalize and store ----
#pragma unroll
    for (int i = 0; i < 4; ++i) {
        float inv = 1.f / lrow[orow + i];
        float4 o0, o1;
        o0.x = O[i][0] * inv; o0.y = O[i][1] * inv;
        o0.z = O[i][2] * inv; o0.w = O[i][3] * inv;
        o1.x = O[i][4] * inv; o1.y = O[i][5] * inv;
        o1.z = O[i][6] * inv; o1.w = O[i][7] * inv;
        long r = qbase + orow + i;
        *(float4*)&o[r * VCOLS + h * DV_ + odv]     = o0;
        *(float4*)&o[r * VCOLS + h * DV_ + odv + 4] = o1;
    }
}

// =====================================================================
// Host launcher
// =====================================================================
extern "C" void kernel_launch(void* const* d_in, const int* in_sizes, int n_in,
                              void* d_out, int out_size, void* d_ws, size_t ws_size,
                              hipStream_t stream)
{
    const float* x         = (const float*)d_in[0];   // (2048, 2048)
    const float* wq_down   = (const float*)d_in[1];   // (2048, 1536)
    const float* q_norm_w  = (const float*)d_in[2];   // (1536,)
    const float* wq_up     = (const float*)d_in[3];   // (1536, 3072)
    const float* wkv_down  = (const float*)d_in[4];   // (2048, 512)
    const float* kv_norm_w = (const float*)d_in[5];   // (512,)
    const float* wk_up     = (const float*)d_in[6];   // (512, 3072)
    const float* wv_up     = (const float*)d_in[7];   // (512, 2048)
    const float* wo        = (const float*)d_in[8];   // (2048, 2048)
    float* out = (float*)d_out;

    float* ws = (float*)d_ws;
    float* q_lat    = ws;                          // 2048*1536 = 3,145,728
    float* kv_lat   = q_lat  + 3145728;            // 2048*512  = 1,048,576
    float* qbuf     = kv_lat + 1048576;            // 2048*3072 = 6,291,456
    float* kbuf     = qbuf   + 6291456;            // 6,291,456
    float* vbuf     = kbuf   + 6291456;            // 2048*2048 = 4,194,304
    float* attn_out = q_lat;                       // alias q_lat+kv_lat (4,194,304) — dead by then
    float* cost     = vbuf + 4194304;              // 2048*32
    float* sint     = cost + 65536;                // 2048*32
    // total ws use: ~84.9 MB

    // 1) q_lat_raw = x @ wq_down   (2048x2048x1536)
    gemm_f32<128,128,8,8><<<dim3(QR_/128, S_LEN/128), 256, 0, stream>>>(
        x, wq_down, q_lat, S_LEN, QR_, H_);
    // 2) kv_lat_raw = x @ wkv_down (2048x2048x512) — 64-tile for grid occupancy
    gemm_f32<64,64,4,4><<<dim3(KVR_/64, S_LEN/64), 256, 0, stream>>>(
        x, wkv_down, kv_lat, S_LEN, KVR_, H_);
    // 3) RMSNorm both latents (in place)
    rmsnorm_k<<<S_LEN, 256, 0, stream>>>(q_lat,  q_norm_w,  QR_,  1.0f / QR_);
    rmsnorm_k<<<S_LEN, 256, 0, stream>>>(kv_lat, kv_norm_w, KVR_, 1.0f / KVR_);
    // 4) q = q_lat @ wq_up (2048x1536x3072)
    gemm_f32<128,128,8,8><<<dim3(QCOLS/128, S_LEN/128), 256, 0, stream>>>(
        q_lat, wq_up, qbuf, S_LEN, QCOLS, QR_);
    // 5) k = kv_lat @ wk_up (2048x512x3072)
    gemm_f32<128,128,8,8><<<dim3(QCOLS/128, S_LEN/128), 256, 0, stream>>>(
        kv_lat, wk_up, kbuf, S_LEN, QCOLS, KVR_);
    // 6) v = kv_lat @ wv_up (2048x512x2048)
    gemm_f32<128,128,8,8><<<dim3(VCOLS/128, S_LEN/128), 256, 0, stream>>>(
        kv_lat, wv_up, vbuf, S_LEN, VCOLS, KVR_);
    // 7) RoPE tables + apply to q_pe / k_pe
    rope_table_k<<<(S_LEN * 32) / 256, 256, 0, stream>>>(cost, sint);
    rope_apply_k<<<(S_LEN * NHEAD * 32) / 256, 256, 0, stream>>>(qbuf, cost, sint);
    rope_apply_k<<<(S_LEN * NHEAD * 32) / 256, 256, 0, stream>>>(kbuf, cost, sint);
    // 8) causal flash attention -> attn_out (2048 x 2048)
    attn_k<<<dim3(S_LEN / QB, NHEAD), 256, 0, stream>>>(qbuf, kbuf, vbuf, attn_out);
    // 9) out = attn_out @ wo (2048x2048x2048)
    gemm_f32<128,128,8,8><<<dim3(H_/128, S_LEN/128), 256, 0, stream>>>(
        attn_out, wo, out, S_LEN, H_, H_);
}

// Round 2
// 609.760 us; speedup vs baseline: 4.2877x; 4.2877x over previous
//
#include <hip/hip_runtime.h>
#include <math.h>

typedef unsigned short u16;
typedef short s16x8 __attribute__((ext_vector_type(8)));
typedef __bf16 bf16x8 __attribute__((ext_vector_type(8)));
typedef float f32x4 __attribute__((ext_vector_type(4)));

#define S_LEN 2048
#define NHEAD 16
#define QCOLS 3072        // NH*192
#define VCOLS 2048        // NH*128
#define ATT_SCALE 0.07216878364870323f   // 1/sqrt(192)

__device__ __forceinline__ u16 f2bf(float f) {
    unsigned u = __float_as_uint(f);
    u += 0x7fffu + ((u >> 16) & 1u);      // RNE
    return (u16)(u >> 16);
}
__device__ __forceinline__ float bf2f(u16 h) {
    return __uint_as_float(((unsigned)h) << 16);
}

// global -> LDS direct (16B/lane). LDS dest is wave-uniform base + lane*16.
typedef const __attribute__((address_space(1))) void gas_void;
typedef __attribute__((address_space(3))) void las_void;
__device__ __forceinline__ void gload_lds16(const void* g, void* l) {
    __builtin_amdgcn_global_load_lds(
        (gas_void*)(unsigned long long)g,
        (las_void*)(unsigned)(unsigned long long)l, 16, 0, 0);
}

// =====================================================================
// bf16 MFMA GEMM: C = A[M][K](bf16) @ Bt[N][K](bf16, pre-transposed).
// 256 thr = 4 waves in 2x2; BK=32; m97 structure (linear LDS + gload_lds).
// =====================================================================
template<int BM, int BN, bool OBF>
__global__ __launch_bounds__(256) void gemm_bf16(
    const u16* __restrict__ A, const u16* __restrict__ Bt,
    void* __restrict__ Cv, int M, int N, int K)
{
    __shared__ u16 As[BM * 32];   // [BM][32] row-major, 64B/row
    __shared__ u16 Bs[BN * 32];
    const int t = threadIdx.x;
    const int lane = t & 63, wid = t >> 6;
    const int wr = wid >> 1, wc = wid & 1;
    const int g = lane >> 4, cl = lane & 15;
    const size_t bm = (size_t)blockIdx.y * BM;
    const size_t bn = (size_t)blockIdx.x * BN;
    constexpr int MR = BM / 32, NR = BN / 32;
    constexpr int ARn = BM / 64, BRn = BN / 64;   // gload rounds per wave

    f32x4 acc[MR][NR] = {};

    for (int k0 = 0; k0 < K; k0 += 32) {
#pragma unroll
        for (int i = 0; i < ARn; ++i) {
            int rnd = wid * ARn + i;
            int flat = (rnd << 10) + (lane << 4);       // byte in As
            int row = flat >> 6;
            int ke  = (flat & 63) >> 1;                 // bf16 elems
            gload_lds16(A + (bm + row) * K + k0 + ke, (char*)As + (rnd << 10));
        }
#pragma unroll
        for (int i = 0; i < BRn; ++i) {
            int rnd = wid * BRn + i;
            int flat = (rnd << 10) + (lane << 4);
            int row = flat >> 6;
            int ke  = (flat & 63) >> 1;
            gload_lds16(Bt + (bn + row) * K + k0 + ke, (char*)Bs + (rnd << 10));
        }
        __syncthreads();   // drains vmcnt(0): gload complete
        s16x8 av[MR], bv[NR];
#pragma unroll
        for (int m = 0; m < MR; ++m)
            av[m] = *(const s16x8*)((const char*)As + (wr*(BM/2) + m*16 + cl)*64 + g*16);
#pragma unroll
        for (int n = 0; n < NR; ++n)
            bv[n] = *(const s16x8*)((const char*)Bs + (wc*(BN/2) + n*16 + cl)*64 + g*16);
#pragma unroll
        for (int m = 0; m < MR; ++m)
#pragma unroll
            for (int n = 0; n < NR; ++n)
                acc[m][n] = __builtin_amdgcn_mfma_f32_16x16x32_bf16(
                    __builtin_bit_cast(bf16x8, av[m]),
                    __builtin_bit_cast(bf16x8, bv[n]), acc[m][n], 0, 0, 0);
        __syncthreads();
    }
    // epilogue: C layout col=lane&15, row=(lane>>4)*4+j (m89-verified)
#pragma unroll
    for (int m = 0; m < MR; ++m)
#pragma unroll
        for (int n = 0; n < NR; ++n) {
            size_t col = bn + wc*(BN/2) + n*16 + cl;
#pragma unroll
            for (int j = 0; j < 4; ++j) {
                size_t row = bm + wr*(BM/2) + m*16 + g*4 + j;
                if constexpr (OBF) ((u16*)Cv)[row * N + col] = f2bf(acc[m][n][j]);
                else               ((float*)Cv)[row * N + col] = acc[m][n][j];
            }
        }
}

// =====================================================================
// Transpose + cast: in fp32 [K][N] -> out bf16 [N][K]. 32x32 tiles.
// =====================================================================
__global__ __launch_bounds__(256) void transpose_cast(
    const float* __restrict__ in, u16* __restrict__ out, int K, int N)
{
    __shared__ float tile[32][33];
    const int bk = blockIdx.y * 32, bn = blockIdx.x * 32;
    const int tx = threadIdx.x & 31, ty = threadIdx.x >> 5;
#pragma unroll
    for (int r = 0; r < 32; r += 8)
        tile[ty + r][tx] = in[(size_t)(bk + ty + r) * N + bn + tx];
    __syncthreads();
#pragma unroll
    for (int r = 0; r < 32; r += 8)
        out[(size_t)(bn + ty + r) * K + bk + tx] = f2bf(tile[tx][ty + r]);
}

__global__ __launch_bounds__(256) void cast_f32_bf16(
    const float* __restrict__ in, u16* __restrict__ out, long n)
{
    long i = ((long)blockIdx.x * 256 + threadIdx.x) * 4;
    if (i >= n) return;
    f32x4 v = *(const f32x4*)(in + i);
    ushort4 q;
    q.x = f2bf(v[0]); q.y = f2bf(v[1]); q.z = f2bf(v[2]); q.w = f2bf(v[3]);
    *(ushort4*)(out + i) = q;
}

// =====================================================================
// RMSNorm: fp32 in -> bf16 out (one block per row)
// =====================================================================
__global__ __launch_bounds__(256) void rmsnorm_bf(
    const float* __restrict__ x, const float* __restrict__ w,
    u16* __restrict__ o, int N, float invN)
{
    const int row = blockIdx.x;
    const float* xr = x + (size_t)row * N;
    u16* orow = o + (size_t)row * N;
    const int t = threadIdx.x;
    float ss = 0.f;
    for (int i = t * 4; i < N; i += 1024) {
        f32x4 v = *(const f32x4*)&xr[i];
        ss += v[0]*v[0] + v[1]*v[1] + v[2]*v[2] + v[3]*v[3];
    }
#pragma unroll
    for (int off = 32; off > 0; off >>= 1) ss += __shfl_down(ss, off, 64);
    __shared__ float red[4];
    __shared__ float sinv;
    if ((t & 63) == 0) red[t >> 6] = ss;
    __syncthreads();
    if (t == 0) sinv = rsqrtf((red[0]+red[1]+red[2]+red[3]) * invN + 1e-5f);
    __syncthreads();
    const float si = sinv;
    for (int i = t * 4; i < N; i += 1024) {
        f32x4 v = *(const f32x4*)&xr[i];
        f32x4 wv = *(const f32x4*)&w[i];
        ushort4 q;
        q.x = f2bf(v[0]*wv[0]*si); q.y = f2bf(v[1]*wv[1]*si);
        q.z = f2bf(v[2]*wv[2]*si); q.w = f2bf(v[3]*wv[3]*si);
        *(ushort4*)&orow[i] = q;
    }
}

// =====================================================================
// RoPE table + apply (bf16 q/k, fp32 math)
// =====================================================================
__global__ __launch_bounds__(256) void rope_table_k(
    float* __restrict__ cost, float* __restrict__ sint)
{
    int idx = blockIdx.x * 256 + threadIdx.x;     // S*32
    int tp = idx >> 5, j = idx & 31;
    float invf = powf(100000.0f, -(float)j * (1.0f / 32.0f));
    float fr = (float)tp * invf;
    cost[idx] = cosf(fr);
    sint[idx] = sinf(fr);
}

__global__ __launch_bounds__(256) void rope_apply_bf(
    u16* __restrict__ qk, const float* __restrict__ cost,
    const float* __restrict__ sint)
{
    int idx = blockIdx.x * 256 + threadIdx.x;     // S*NH*32
    int j = idx & 31, hh = (idx >> 5) & 15, s = idx >> 9;
    u16* p = qk + (size_t)s * QCOLS + hh * 192 + 128;
    float a = bf2f(p[j]), b = bf2f(p[j + 32]);
    float co = cost[(s << 5) + j], sn = sint[(s << 5) + j];
    p[j]      = f2bf(fmaf(a, co, -b * sn));
    p[j + 32] = f2bf(fmaf(b, co,  a * sn));
}

// =====================================================================
// Attention: MFMA QK^T + wave-parallel online softmax (regs) + fp32 VALU PV.
// grid (32, 16); 256 thr = 4 waves, each wave owns 16 q-rows. KB tile 64.
// K in LDS bf16 XOR-swizzled; V in LDS fp32 (gload); P^T[kv][q] in LDS.
// =====================================================================
__global__ __launch_bounds__(256) void attn_mfma(
    const u16* __restrict__ qg, const u16* __restrict__ kg,
    const float* __restrict__ vg, u16* __restrict__ og)
{
    __shared__ u16  Ks[64 * 192];      // 24KB, swizzled: byte ^= (row&7)<<4
    __shared__ float Vs[64][128];      // 32KB
    __shared__ float Pst[64][68];      // [kv][q], 17.4KB, rows 16B-aligned
    __shared__ float crow[64], lrow[64];

    const int t = threadIdx.x, lane = t & 63, wid = t >> 6;
    const int g = lane >> 4, cl = lane & 15;
    const int h = blockIdx.y;
    const int bx = blockIdx.x;
    const int qt = (bx & 1) ? (31 - (bx >> 1)) : (bx >> 1);  // causal balance pairs
    const int qbase = qt * 64;
    const int wrow = wid * 16;

    // Q fragments in registers (A-operand: row=lane&15, k=(lane>>4)*8+j)
    s16x8 qv[6];
    {
        const u16* qrow = qg + (size_t)(qbase + wrow + cl) * QCOLS + h * 192;
#pragma unroll
        for (int s = 0; s < 6; ++s)
            qv[s] = *(const s16x8*)(qrow + s * 32 + g * 8);
    }
    float mreg[4], lreg[4];
#pragma unroll
    for (int j = 0; j < 4; ++j) { mreg[j] = -1e30f; lreg[j] = 0.f; }

    const int pg = t >> 4;       // PV: rows pg*4..+3
    const int px = t & 15;       // PV: cols px*4 and 64+px*4
    float O[4][8] = {};

    for (int kt = 0; kt <= qt; ++kt) {
        const int kbase = kt * 64;
        __syncthreads();   // prev tile fully consumed (Ks/Vs/Pst reusable)
        // ---- stage K (bf16, swizzled via reg) ----
        {
            const u16* ksrc = kg + (size_t)kbase * QCOLS + h * 192;
#pragma unroll
            for (int p = 0; p < 6; ++p) {
                int idx = (p * 256 + t) << 4;    // byte in 24576
                int row = idx / 384;
                int cb  = idx % 384;
                s16x8 d = *(const s16x8*)(ksrc + (size_t)row * QCOLS + (cb >> 1));
                *(s16x8*)((char*)Ks + row * 384 + (cb ^ ((row & 7) << 4))) = d;
            }
            // ---- stage V (fp32, linear, direct-to-LDS) ----
            const char* vsrc = (const char*)(vg + (size_t)kbase * VCOLS + h * 128);
#pragma unroll
            for (int i = 0; i < 8; ++i) {
                int rnd = wid * 8 + i;
                int fb = (rnd << 10) + (lane << 4);
                int row = fb >> 9;               // 512B per V row
                int cb  = fb & 511;
                gload_lds16(vsrc + (size_t)row * (VCOLS * 4) + cb,
                            (char*)Vs + (rnd << 10));
            }
        }
        __syncthreads();

        // ---- QK^T: S[16q][64kv] per wave ----
        f32x4 accS[4] = {};
#pragma unroll
        for (int n = 0; n < 4; ++n) {
            const int kvrow = n * 16 + cl;
            const char* krow = (const char*)Ks + kvrow * 384;
            const int sw = (kvrow & 7) << 4;
#pragma unroll
            for (int s = 0; s < 6; ++s) {
                s16x8 kv8 = *(const s16x8*)(krow + ((s * 64 + g * 16) ^ sw));
                accS[n] = __builtin_amdgcn_mfma_f32_16x16x32_bf16(
                    __builtin_bit_cast(bf16x8, qv[s]),
                    __builtin_bit_cast(bf16x8, kv8), accS[n], 0, 0, 0);
            }
        }
        // ---- mask + scale + online softmax (all lanes; rows g*4+j) ----
        float pm[4][4];   // [n][j]
#pragma unroll
        for (int j = 0; j < 4; ++j) {
            const int qrow = qbase + wrow + g * 4 + j;
            float mx = -1e30f;
#pragma unroll
            for (int n = 0; n < 4; ++n) {
                int kcol = kbase + n * 16 + cl;
                float s = accS[n][j] * ATT_SCALE;
                s = (kcol <= qrow) ? s : -1e30f;
                pm[n][j] = s;
                mx = fmaxf(mx, s);
            }
#pragma unroll
            for (int off = 1; off < 16; off <<= 1)
                mx = fmaxf(mx, __shfl_xor(mx, off, 64));
            float mnew = fmaxf(mreg[j], mx);
            float c = __expf(mreg[j] - mnew);
            float rs = 0.f;
#pragma unroll
            for (int n = 0; n < 4; ++n) {
                float p = __expf(pm[n][j] - mnew);
                pm[n][j] = p;
                rs += p;
            }
#pragma unroll
            for (int off = 1; off < 16; off <<= 1)
                rs += __shfl_xor(rs, off, 64);
            lreg[j] = lreg[j] * c + rs;
            mreg[j] = mnew;
            if (cl == 0) crow[wrow + g * 4 + j] = c;
        }
        // write P transposed: Pst[kv][q]
#pragma unroll
        for (int n = 0; n < 4; ++n)
#pragma unroll
            for (int j = 0; j < 4; ++j)
                Pst[n * 16 + cl][wrow + g * 4 + j] = pm[n][j];
        __syncthreads();

        // ---- PV (fp32 VALU) ----
        float cc[4];
#pragma unroll
        for (int i = 0; i < 4; ++i) cc[i] = crow[pg * 4 + i];
#pragma unroll
        for (int i = 0; i < 4; ++i)
#pragma unroll
            for (int jj = 0; jj < 8; ++jj) O[i][jj] *= cc[i];
#pragma unroll 4
        for (int j = 0; j < 64; ++j) {
            f32x4 va = *(const f32x4*)&Vs[j][px * 4];
            f32x4 vb = *(const f32x4*)&Vs[j][64 + px * 4];
            f32x4 pr = *(const f32x4*)&Pst[j][pg * 4];
#pragma unroll
            for (int i = 0; i < 4; ++i) {
                float p = pr[i];
                O[i][0] = fmaf(p, va[0], O[i][0]);
                O[i][1] = fmaf(p, va[1], O[i][1]);
                O[i][2] = fmaf(p, va[2], O[i][2]);
                O[i][3] = fmaf(p, va[3], O[i][3]);
                O[i][4] = fmaf(p, vb[0], O[i][4]);
                O[i][5] = fmaf(p, vb[1], O[i][5]);
                O[i][6] = fmaf(p, vb[2], O[i][6]);
                O[i][7] = fmaf(p, vb[3], O[i][7]);
            }
        }
    }

    // ---- epilogue ----
    if (cl == 0) {
#pragma unroll
        for (int j = 0; j < 4; ++j) lrow[wrow + g * 4 + j] = lreg[j];
    }
    __syncthreads();
#pragma unroll
    for (int i = 0; i < 4; ++i) {
        float inv = 1.f / lrow[pg * 4 + i];
        u16* orow = og + (size_t)(qbase + pg * 4 + i) * VCOLS + h * 128;
        ushort4 o0, o1;
        o0.x = f2bf(O[i][0]*inv); o0.y = f2bf(O[i][1]*inv);
        o0.z = f2bf(O[i][2]*inv); o0.w = f2bf(O[i][3]*inv);
        o1.x = f2bf(O[i][4]*inv); o1.y = f2bf(O[i][5]*inv);
        o1.z = f2bf(O[i][6]*inv); o1.w = f2bf(O[i][7]*inv);
        *(ushort4*)(orow + px * 4)      = o0;
        *(ushort4*)(orow + 64 + px * 4) = o1;
    }
}

// =====================================================================
// Host launcher
// =====================================================================
extern "C" void kernel_launch(void* const* d_in, const int* in_sizes, int n_in,
                              void* d_out, int out_size, void* d_ws, size_t ws_size,
                              hipStream_t stream)
{
    const float* x         = (const float*)d_in[0];
    const float* wq_down   = (const float*)d_in[1];
    const float* q_norm_w  = (const float*)d_in[2];
    const float* wq_up     = (const float*)d_in[3];
    const float* wkv_down  = (const float*)d_in[4];
    const float* kv_norm_w = (const float*)d_in[5];
    const float* wk_up     = (const float*)d_in[6];
    const float* wv_up     = (const float*)d_in[7];
    const float* wo        = (const float*)d_in[8];
    float* out = (float*)d_out;
    char* ws = (char*)d_ws;

    u16*  WQD_T  = (u16*)(ws + 0);            // 6,291,456 B
    u16*  WKVD_T = (u16*)(ws + 6291456);      // 2,097,152
    u16*  WQU_T  = (u16*)(ws + 8388608);      // 9,437,184
    u16*  WKU_T  = (u16*)(ws + 17825792);     // 3,145,728
    u16*  WVU_T  = (u16*)(ws + 20971520);     // 2,097,152
    u16*  XBF    = (u16*)(ws + 23068672);     // 8,388,608
    float* QLAT  = (float*)(ws + 31457280);   // 12,582,912
    float* KVLAT = (float*)(ws + 44040192);   // 4,194,304
    u16*  QLATB  = (u16*)(ws + 48234496);     // 6,291,456
    u16*  KVLATB = (u16*)(ws + 54525952);     // 2,097,152
    u16*  QBUF   = (u16*)(ws + 56623104);     // 12,582,912
    u16*  KBUF   = (u16*)(ws + 69206016);     // 12,582,912
    float* COST  = (float*)(ws + 81788928);   // 262,144
    float* SINT  = (float*)(ws + 82051072);   // 262,144  (end ~82.3MB)
    // aliases over dead regions:
    u16*  WO_T   = (u16*)(ws + 0);            // 8,388,608 over WQD_T+WKVD_T (dead after gemm1/2)
    float* VBUF  = (float*)(ws + 31457280);   // 16,777,216 over QLAT+KVLAT (dead after rmsnorms)
    u16*  ATTNO  = (u16*)(ws + 23068672);     // over XBF (dead after gemm1/2)

    // weight prep (bf16, transposed to [N][K])
    transpose_cast<<<dim3(48, 64), 256, 0, stream>>>(wq_down,  WQD_T,  2048, 1536);
    transpose_cast<<<dim3(16, 64), 256, 0, stream>>>(wkv_down, WKVD_T, 2048, 512);
    transpose_cast<<<dim3(96, 48), 256, 0, stream>>>(wq_up,    WQU_T,  1536, 3072);
    transpose_cast<<<dim3(96, 16), 256, 0, stream>>>(wk_up,    WKU_T,  512,  3072);
    transpose_cast<<<dim3(64, 16), 256, 0, stream>>>(wv_up,    WVU_T,  512,  2048);
    cast_f32_bf16<<<4096, 256, 0, stream>>>(x, XBF, (long)S_LEN * 2048);

    // down-projections (fp32 out for RMSNorm)
    gemm_bf16<128,128,false><<<dim3(12, 16), 256, 0, stream>>>(XBF, WQD_T,  QLAT,  2048, 1536, 2048);
    gemm_bf16< 64, 64,false><<<dim3( 8, 32), 256, 0, stream>>>(XBF, WKVD_T, KVLAT, 2048,  512, 2048);
    rmsnorm_bf<<<2048, 256, 0, stream>>>(QLAT,  q_norm_w,  QLATB,  1536, 1.f/1536.f);
    rmsnorm_bf<<<2048, 256, 0, stream>>>(KVLAT, kv_norm_w, KVLATB, 512,  1.f/512.f);
    transpose_cast<<<dim3(64, 64), 256, 0, stream>>>(wo, WO_T, 2048, 2048);  // after gemm1/2 read WQD_T

    // up-projections
    gemm_bf16<128,128,true ><<<dim3(24, 16), 256, 0, stream>>>(QLATB,  WQU_T, QBUF, 2048, 3072, 1536);
    gemm_bf16<128,128,true ><<<dim3(24, 16), 256, 0, stream>>>(KVLATB, WKU_T, KBUF, 2048, 3072, 512);
    gemm_bf16<128,128,false><<<dim3(16, 16), 256, 0, stream>>>(KVLATB, WVU_T, VBUF, 2048, 2048, 512);

    // RoPE
    rope_table_k<<<256, 256, 0, stream>>>(COST, SINT);
    rope_apply_bf<<<4096, 256, 0, stream>>>(QBUF, COST, SINT);
    rope_apply_bf<<<4096, 256, 0, stream>>>(KBUF, COST, SINT);

    // attention + output projection
    attn_mfma<<<dim3(32, 16), 256, 0, stream>>>(QBUF, KBUF, VBUF, ATTNO);
    gemm_bf16<128,128,false><<<dim3(16, 16), 256, 0, stream>>>(ATTNO, WO_T, out, 2048, 2048, 2048);
}

// Round 3
// 452.783 us; speedup vs baseline: 5.7742x; 1.3467x over previous
//
#include <hip/hip_runtime.h>
#include <math.h>

typedef unsigned short u16;
typedef short s16x8 __attribute__((ext_vector_type(8)));
typedef __bf16 bf16x8 __attribute__((ext_vector_type(8)));
typedef float f32x4 __attribute__((ext_vector_type(4)));

#define S_LEN 2048
#define NHEAD 16
#define QCOLS 3072        // NH*192
#define VCOLS 2048        // NH*128
#define ATT_SCALE 0.07216878364870323f   // 1/sqrt(192)

__device__ __forceinline__ u16 f2bf(float f) {
    unsigned u = __float_as_uint(f);
    u += 0x7fffu + ((u >> 16) & 1u);      // RNE
    return (u16)(u >> 16);
}
__device__ __forceinline__ float bf2f(u16 h) {
    return __uint_as_float(((unsigned)h) << 16);
}

// global -> LDS direct (16B/lane). LDS dest is wave-uniform base + lane*16.
typedef const __attribute__((address_space(1))) void gas_void;
typedef __attribute__((address_space(3))) void las_void;
__device__ __forceinline__ void gload_lds16(const void* g, void* l) {
    __builtin_amdgcn_global_load_lds(
        (gas_void*)(unsigned long long)g,
        (las_void*)(unsigned)(unsigned long long)l, 16, 0, 0);
}

// =====================================================================
// bf16 MFMA GEMM: C = A[M][K](bf16) @ Bt[N][K](bf16, pre-transposed).
// 256 thr = 4 waves in 2x2; BK=32; m97 structure (linear LDS + gload_lds).
// OMODE: 0 = f32 out, 1 = bf16 out, 2 = bf16 TRANSPOSED out (C^T[N][M]).
// =====================================================================
template<int BM, int BN, int OMODE>
__global__ __launch_bounds__(256) void gemm_bf16(
    const u16* __restrict__ A, const u16* __restrict__ Bt,
    void* __restrict__ Cv, int M, int N, int K)
{
    __shared__ u16 As[BM * 32];   // [BM][32] row-major, 64B/row
    __shared__ u16 Bs[BN * 32];
    const int t = threadIdx.x;
    const int lane = t & 63, wid = t >> 6;
    const int wr = wid >> 1, wc = wid & 1;
    const int g = lane >> 4, cl = lane & 15;
    const size_t bm = (size_t)blockIdx.y * BM;
    const size_t bn = (size_t)blockIdx.x * BN;
    constexpr int MR = BM / 32, NR = BN / 32;
    constexpr int ARn = BM / 64, BRn = BN / 64;   // gload rounds per wave

    f32x4 acc[MR][NR] = {};

    for (int k0 = 0; k0 < K; k0 += 32) {
#pragma unroll
        for (int i = 0; i < ARn; ++i) {
            int rnd = wid * ARn + i;
            int flat = (rnd << 10) + (lane << 4);       // byte in As
            int row = flat >> 6;
            int ke  = (flat & 63) >> 1;                 // bf16 elems
            gload_lds16(A + (bm + row) * K + k0 + ke, (char*)As + (rnd << 10));
        }
#pragma unroll
        for (int i = 0; i < BRn; ++i) {
            int rnd = wid * BRn + i;
            int flat = (rnd << 10) + (lane << 4);
            int row = flat >> 6;
            int ke  = (flat & 63) >> 1;
            gload_lds16(Bt + (bn + row) * K + k0 + ke, (char*)Bs + (rnd << 10));
        }
        __syncthreads();   // drains vmcnt(0): gload complete
        s16x8 av[MR], bv[NR];
#pragma unroll
        for (int m = 0; m < MR; ++m)
            av[m] = *(const s16x8*)((const char*)As + (wr*(BM/2) + m*16 + cl)*64 + g*16);
#pragma unroll
        for (int n = 0; n < NR; ++n)
            bv[n] = *(const s16x8*)((const char*)Bs + (wc*(BN/2) + n*16 + cl)*64 + g*16);
#pragma unroll
        for (int m = 0; m < MR; ++m)
#pragma unroll
            for (int n = 0; n < NR; ++n)
                acc[m][n] = __builtin_amdgcn_mfma_f32_16x16x32_bf16(
                    __builtin_bit_cast(bf16x8, av[m]),
                    __builtin_bit_cast(bf16x8, bv[n]), acc[m][n], 0, 0, 0);
        __syncthreads();
    }
    // epilogue: C layout col=lane&15, row=(lane>>4)*4+j (m89-verified)
#pragma unroll
    for (int m = 0; m < MR; ++m)
#pragma unroll
        for (int n = 0; n < NR; ++n) {
            size_t col = bn + wc*(BN/2) + n*16 + cl;
#pragma unroll
            for (int j = 0; j < 4; ++j) {
                size_t row = bm + wr*(BM/2) + m*16 + g*4 + j;
                if constexpr (OMODE == 0)
                    ((float*)Cv)[row * N + col] = acc[m][n][j];
                else if constexpr (OMODE == 1)
                    ((u16*)Cv)[row * N + col] = f2bf(acc[m][n][j]);
                else
                    ((u16*)Cv)[col * M + row] = f2bf(acc[m][n][j]);
            }
        }
}

// =====================================================================
// Transpose + cast: in fp32 [K][N] -> out bf16 [N][K]. 32x32 tiles.
// =====================================================================
__global__ __launch_bounds__(256) void transpose_cast(
    const float* __restrict__ in, u16* __restrict__ out, int K, int N)
{
    __shared__ float tile[32][33];
    const int bk = blockIdx.y * 32, bn = blockIdx.x * 32;
    const int tx = threadIdx.x & 31, ty = threadIdx.x >> 5;
#pragma unroll
    for (int r = 0; r < 32; r += 8)
        tile[ty + r][tx] = in[(size_t)(bk + ty + r) * N + bn + tx];
    __syncthreads();
#pragma unroll
    for (int r = 0; r < 32; r += 8)
        out[(size_t)(bn + ty + r) * K + bk + tx] = f2bf(tile[tx][ty + r]);
}

__global__ __launch_bounds__(256) void cast_f32_bf16(
    const float* __restrict__ in, u16* __restrict__ out, long n)
{
    long i = ((long)blockIdx.x * 256 + threadIdx.x) * 4;
    if (i >= n) return;
    f32x4 v = *(const f32x4*)(in + i);
    ushort4 q;
    q.x = f2bf(v[0]); q.y = f2bf(v[1]); q.z = f2bf(v[2]); q.w = f2bf(v[3]);
    *(ushort4*)(out + i) = q;
}

// =====================================================================
// RMSNorm: fp32 in -> bf16 out (one block per row)
// =====================================================================
__global__ __launch_bounds__(256) void rmsnorm_bf(
    const float* __restrict__ x, const float* __restrict__ w,
    u16* __restrict__ o, int N, float invN)
{
    const int row = blockIdx.x;
    const float* xr = x + (size_t)row * N;
    u16* orow = o + (size_t)row * N;
    const int t = threadIdx.x;
    float ss = 0.f;
    for (int i = t * 4; i < N; i += 1024) {
        f32x4 v = *(const f32x4*)&xr[i];
        ss += v[0]*v[0] + v[1]*v[1] + v[2]*v[2] + v[3]*v[3];
    }
#pragma unroll
    for (int off = 32; off > 0; off >>= 1) ss += __shfl_down(ss, off, 64);
    __shared__ float red[4];
    __shared__ float sinv;
    if ((t & 63) == 0) red[t >> 6] = ss;
    __syncthreads();
    if (t == 0) sinv = rsqrtf((red[0]+red[1]+red[2]+red[3]) * invN + 1e-5f);
    __syncthreads();
    const float si = sinv;
    for (int i = t * 4; i < N; i += 1024) {
        f32x4 v = *(const f32x4*)&xr[i];
        f32x4 wv = *(const f32x4*)&w[i];
        ushort4 q;
        q.x = f2bf(v[0]*wv[0]*si); q.y = f2bf(v[1]*wv[1]*si);
        q.z = f2bf(v[2]*wv[2]*si); q.w = f2bf(v[3]*wv[3]*si);
        *(ushort4*)&orow[i] = q;
    }
}

// =====================================================================
// RoPE table + apply (bf16 q/k, fp32 math)
// =====================================================================
__global__ __launch_bounds__(256) void rope_table_k(
    float* __restrict__ cost, float* __restrict__ sint)
{
    int idx = blockIdx.x * 256 + threadIdx.x;     // S*32
    int tp = idx >> 5, j = idx & 31;
    float invf = powf(100000.0f, -(float)j * (1.0f / 32.0f));
    float fr = (float)tp * invf;
    cost[idx] = cosf(fr);
    sint[idx] = sinf(fr);
}

__global__ __launch_bounds__(256) void rope_apply_bf(
    u16* __restrict__ qk, const float* __restrict__ cost,
    const float* __restrict__ sint)
{
    int idx = blockIdx.x * 256 + threadIdx.x;     // S*NH*32
    int j = idx & 31, hh = (idx >> 5) & 15, s = idx >> 9;
    u16* p = qk + (size_t)s * QCOLS + hh * 192 + 128;
    float a = bf2f(p[j]), b = bf2f(p[j + 32]);
    float co = cost[(s << 5) + j], sn = sint[(s << 5) + j];
    p[j]      = f2bf(fmaf(a, co, -b * sn));
    p[j + 32] = f2bf(fmaf(b, co,  a * sn));
}

// =====================================================================
// Attention, fully-MFMA: QK^T MFMA + register online softmax + PV MFMA.
// grid (32, 16); 256 thr = 4 waves; wave owns 16 q-rows. KV tile 64.
// K: LDS bf16, XOR-swizzled (byte^=(row&7)<<4), staged via gload_lds with
//    pre-swizzled global source (rule #21).
// VT: V pre-transposed in global [dv][token] bf16; LDS tile [128][64] bf16,
//    same swizzle scheme, gload_lds + pre-swizzled source.
// P: per-wave-private LDS [16 q][64 kv] bf16 (swizzled); written from the
//    QK^T C-layout, read back as 16x16x32 A-fragments (one b128 each).
// =====================================================================
__global__ __launch_bounds__(256) void attn_mfma(
    const u16* __restrict__ qg, const u16* __restrict__ kg,
    const u16* __restrict__ vtg, u16* __restrict__ og)
{
    __shared__ u16 Ks[64 * 192];       // 24KB, row 384B, swz (row&7)<<4
    __shared__ u16 VTs[128 * 64];      // 16KB, row 128B, swz (dv&7)<<4
    __shared__ u16 Ps[4][16 * 64];     // 8KB, per-wave, row 128B, swz (q&7)<<4

    const int t = threadIdx.x, lane = t & 63, wid = t >> 6;
    const int g = lane >> 4, cl = lane & 15;
    const int h = blockIdx.y;
    const int bx = blockIdx.x;
    const int qt = (bx & 1) ? (31 - (bx >> 1)) : (bx >> 1);  // causal balance
    const int qbase = qt * 64;
    const int wrow = wid * 16;

    // Q fragments (A-operand: row=lane&15, k=(lane>>4)*8+j)
    s16x8 qv[6];
    {
        const u16* qrow = qg + (size_t)(qbase + wrow + cl) * QCOLS + h * 192;
#pragma unroll
        for (int s = 0; s < 6; ++s)
            qv[s] = *(const s16x8*)(qrow + s * 32 + g * 8);
    }
    float mreg[4], lreg[4];
#pragma unroll
    for (int j = 0; j < 4; ++j) { mreg[j] = -1e30f; lreg[j] = 0.f; }

    f32x4 accO[8] = {};    // O[q=g*4+j][dv=nb*16+cl]
    char* pw = (char*)Ps[wid];

    for (int kt = 0; kt <= qt; ++kt) {
        const int kbase = kt * 64;
        __syncthreads();   // prev tile's Ks/VTs fully consumed
        // ---- stage K: 24 rounds of 1KB, 6 per wave, pre-swizzled src ----
        {
            const char* ksrc = (const char*)(kg + (size_t)kbase * QCOLS + h * 192);
#pragma unroll
            for (int i = 0; i < 6; ++i) {
                int rnd = wid * 6 + i;
                int fb  = (rnd << 10) + (lane << 4);
                int row = fb / 384;
                int cb  = fb - row * 384;
                gload_lds16(ksrc + (size_t)row * (QCOLS * 2)
                                 + (cb ^ ((row & 7) << 4)),
                            (char*)Ks + (rnd << 10));
            }
            // ---- stage VT: 16 rounds of 1KB, 4 per wave ----
            const char* vsrc = (const char*)(vtg + (size_t)(h * 128) * S_LEN + kbase);
#pragma unroll
            for (int i = 0; i < 4; ++i) {
                int rnd = wid * 4 + i;
                int fb  = (rnd << 10) + (lane << 4);
                int dv  = fb >> 7;
                int cb  = fb & 127;
                gload_lds16(vsrc + (size_t)dv * (S_LEN * 2)
                                 + (cb ^ ((dv & 7) << 4)),
                            (char*)VTs + (rnd << 10));
            }
        }
        __syncthreads();

        // ---- QK^T: S[16q][64kv] per wave ----
        f32x4 accS[4] = {};
#pragma unroll
        for (int n = 0; n < 4; ++n) {
            const int kvrow = n * 16 + cl;
            const char* krow = (const char*)Ks + kvrow * 384;
            const int sw = (kvrow & 7) << 4;
#pragma unroll
            for (int s = 0; s < 6; ++s) {
                s16x8 kv8 = *(const s16x8*)(krow + ((s * 64 + g * 16) ^ sw));
                accS[n] = __builtin_amdgcn_mfma_f32_16x16x32_bf16(
                    __builtin_bit_cast(bf16x8, qv[s]),
                    __builtin_bit_cast(bf16x8, kv8), accS[n], 0, 0, 0);
            }
        }

        // ---- mask + scale + online softmax (rows g*4+j, all lanes) ----
        float pm[4][4];   // [n][j]
        float cj[4];
#pragma unroll
        for (int j = 0; j < 4; ++j) {
            const int qrow = qbase + wrow + g * 4 + j;
            float mx = -1e30f;
#pragma unroll
            for (int n = 0; n < 4; ++n) {
                int kcol = kbase + n * 16 + cl;
                float s = accS[n][j] * ATT_SCALE;
                s = (kcol <= qrow) ? s : -1e30f;
                pm[n][j] = s;
                mx = fmaxf(mx, s);
            }
#pragma unroll
            for (int off = 1; off < 16; off <<= 1)
                mx = fmaxf(mx, __shfl_xor(mx, off, 64));
            float mnew = fmaxf(mreg[j], mx);
            float c = __expf(mreg[j] - mnew);
            float rs = 0.f;
#pragma unroll
            for (int n = 0; n < 4; ++n) {
                float p = __expf(pm[n][j] - mnew);
                pm[n][j] = p;
                rs += p;
            }
#pragma unroll
            for (int off = 1; off < 16; off <<= 1)
                rs += __shfl_xor(rs, off, 64);
            lreg[j] = lreg[j] * c + rs;
            mreg[j] = mnew;
            cj[j] = c;
        }

        // ---- write P (bf16) into per-wave LDS tile [q][kv], swizzled ----
#pragma unroll
        for (int n = 0; n < 4; ++n)
#pragma unroll
            for (int j = 0; j < 4; ++j) {
                int q = g * 4 + j;
                int byte = (q * 128 + (n * 16 + cl) * 2) ^ ((q & 7) << 4);
                *(u16*)(pw + byte) = f2bf(pm[n][j]);
            }

        // ---- rescale O, then PV via MFMA ----
#pragma unroll
        for (int nb = 0; nb < 8; ++nb)
#pragma unroll
            for (int j = 0; j < 4; ++j) accO[nb][j] *= cj[j];

#pragma unroll
        for (int ks = 0; ks < 2; ++ks) {
            s16x8 pa = *(const s16x8*)(pw +
                ((cl * 128 + ks * 64 + g * 16) ^ ((cl & 7) << 4)));
#pragma unroll
            for (int nb = 0; nb < 8; ++nb) {
                s16x8 vb = *(const s16x8*)((const char*)VTs +
                    (((nb * 16 + cl) * 128 + ks * 64 + g * 16) ^ ((cl & 7) << 4)));
                accO[nb] = __builtin_amdgcn_mfma_f32_16x16x32_bf16(
                    __builtin_bit_cast(bf16x8, pa),
                    __builtin_bit_cast(bf16x8, vb), accO[nb], 0, 0, 0);
            }
        }
    }

    // ---- epilogue: O /= l, store bf16 ----
#pragma unroll
    for (int j = 0; j < 4; ++j) {
        float inv = 1.f / lreg[j];
        u16* orow = og + (size_t)(qbase + wrow + g * 4 + j) * VCOLS + h * 128;
#pragma unroll
        for (int nb = 0; nb < 8; ++nb)
            orow[nb * 16 + cl] = f2bf(accO[nb][j] * inv);
    }
}

// =====================================================================
// Host launcher
// =====================================================================
extern "C" void kernel_launch(void* const* d_in, const int* in_sizes, int n_in,
                              void* d_out, int out_size, void* d_ws, size_t ws_size,
                              hipStream_t stream)
{
    const float* x         = (const float*)d_in[0];
    const float* wq_down   = (const float*)d_in[1];
    const float* q_norm_w  = (const float*)d_in[2];
    const float* wq_up     = (const float*)d_in[3];
    const float* wkv_down  = (const float*)d_in[4];
    const float* kv_norm_w = (const float*)d_in[5];
    const float* wk_up     = (const float*)d_in[6];
    const float* wv_up     = (const float*)d_in[7];
    const float* wo        = (const float*)d_in[8];
    float* out = (float*)d_out;
    char* ws = (char*)d_ws;

    u16*  WQD_T  = (u16*)(ws + 0);            // 6,291,456 B
    u16*  WKVD_T = (u16*)(ws + 6291456);      // 2,097,152
    u16*  WQU_T  = (u16*)(ws + 8388608);      // 9,437,184
    u16*  WKU_T  = (u16*)(ws + 17825792);     // 3,145,728
    u16*  WVU_T  = (u16*)(ws + 20971520);     // 2,097,152
    u16*  XBF    = (u16*)(ws + 23068672);     // 8,388,608
    float* QLAT  = (float*)(ws + 31457280);   // 12,582,912
    float* KVLAT = (float*)(ws + 44040192);   // 4,194,304
    u16*  QLATB  = (u16*)(ws + 48234496);     // 6,291,456
    u16*  KVLATB = (u16*)(ws + 54525952);     // 2,097,152
    u16*  QBUF   = (u16*)(ws + 56623104);     // 12,582,912
    u16*  KBUF   = (u16*)(ws + 69206016);     // 12,582,912
    float* COST  = (float*)(ws + 81788928);   // 262,144
    float* SINT  = (float*)(ws + 82051072);   // 262,144
    // aliases over dead regions:
    u16*  WO_T   = (u16*)(ws + 0);            // over WQD_T+WKVD_T (dead after down-proj)
    u16*  VTBUF  = (u16*)(ws + 31457280);     // 8,388,608 over QLAT (dead after rmsnorm)
    u16*  ATTNO  = (u16*)(ws + 23068672);     // over XBF (dead after down-proj)

    // weight prep (bf16, transposed to [N][K])
    transpose_cast<<<dim3(48, 64), 256, 0, stream>>>(wq_down,  WQD_T,  2048, 1536);
    transpose_cast<<<dim3(16, 64), 256, 0, stream>>>(wkv_down, WKVD_T, 2048, 512);
    transpose_cast<<<dim3(96, 48), 256, 0, stream>>>(wq_up,    WQU_T,  1536, 3072);
    transpose_cast<<<dim3(96, 16), 256, 0, stream>>>(wk_up,    WKU_T,  512,  3072);
    transpose_cast<<<dim3(64, 16), 256, 0, stream>>>(wv_up,    WVU_T,  512,  2048);
    cast_f32_bf16<<<4096, 256, 0, stream>>>(x, XBF, (long)S_LEN * 2048);

    // down-projections (fp32 out for RMSNorm)
    gemm_bf16<128,128,0><<<dim3(12, 16), 256, 0, stream>>>(XBF, WQD_T,  QLAT,  2048, 1536, 2048);
    gemm_bf16< 64, 64,0><<<dim3( 8, 32), 256, 0, stream>>>(XBF, WKVD_T, KVLAT, 2048,  512, 2048);
    rmsnorm_bf<<<2048, 256, 0, stream>>>(QLAT,  q_norm_w,  QLATB,  1536, 1.f/1536.f);
    rmsnorm_bf<<<2048, 256, 0, stream>>>(KVLAT, kv_norm_w, KVLATB, 512,  1.f/512.f);
    transpose_cast<<<dim3(64, 64), 256, 0, stream>>>(wo, WO_T, 2048, 2048);

    // up-projections (V written TRANSPOSED: VT[dv][token])
    gemm_bf16<128,128,1><<<dim3(24, 16), 256, 0, stream>>>(QLATB,  WQU_T, QBUF,  2048, 3072, 1536);
    gemm_bf16<128,128,1><<<dim3(24, 16), 256, 0, stream>>>(KVLATB, WKU_T, KBUF,  2048, 3072, 512);
    gemm_bf16<128,128,2><<<dim3(16, 16), 256, 0, stream>>>(KVLATB, WVU_T, VTBUF, 2048, 2048, 512);

    // RoPE
    rope_table_k<<<256, 256, 0, stream>>>(COST, SINT);
    rope_apply_bf<<<4096, 256, 0, stream>>>(QBUF, COST, SINT);
    rope_apply_bf<<<4096, 256, 0, stream>>>(KBUF, COST, SINT);

    // attention + output projection
    attn_mfma<<<dim3(32, 16), 256, 0, stream>>>(QBUF, KBUF, VTBUF, ATTNO);
    gemm_bf16<128,128,0><<<dim3(16, 16), 256, 0, stream>>>(ATTNO, WO_T, out, 2048, 2048, 2048);
}

// Round 4
// 375.173 us; speedup vs baseline: 6.9686x; 1.2069x over previous
//
#include <hip/hip_runtime.h>
#include <math.h>

typedef unsigned short u16;
typedef short s16x8 __attribute__((ext_vector_type(8)));
typedef __bf16 bf16x8 __attribute__((ext_vector_type(8)));
typedef float f32x4 __attribute__((ext_vector_type(4)));

#define S_LEN 2048
#define NHEAD 16
#define QCOLS 3072        // NH*192
#define VCOLS 2048        // NH*128
#define ATT_SCALE 0.07216878364870323f   // 1/sqrt(192)

__device__ __forceinline__ u16 f2bf(float f) {
    unsigned u = __float_as_uint(f);
    u += 0x7fffu + ((u >> 16) & 1u);      // RNE
    return (u16)(u >> 16);
}
__device__ __forceinline__ float bf2f(u16 h) {
    return __uint_as_float(((unsigned)h) << 16);
}

// global -> LDS direct (16B/lane). LDS dest is wave-uniform base + lane*16.
typedef const __attribute__((address_space(1))) void gas_void;
typedef __attribute__((address_space(3))) void las_void;
__device__ __forceinline__ void gload_lds16(const void* g, void* l) {
    __builtin_amdgcn_global_load_lds(
        (gas_void*)(unsigned long long)g,
        (las_void*)(unsigned)(unsigned long long)l, 16, 0, 0);
}

// =====================================================================
// bf16 MFMA GEMM, 2-phase prefetch (T3-minimum): C = A[M][K] @ Bt[N][K].
// 256 thr = 4 waves (2x2); BK=64; double-buffered LDS; stage(t+1) issued
// before compute(t); loop-top __syncthreads drains vmcnt.
// OMODE: 0 f32 out | 1 bf16 out | 2 bf16 transposed out | 3 bf16 + RoPE
// (OMODE 3: N must be 3072; PE 64-bands are band%3==2, pair n <-> n+2.)
// =====================================================================
template<int BM, int BN, int OMODE>
__global__ __launch_bounds__(256) void gemm_bf16(
    const u16* __restrict__ A, const u16* __restrict__ Bt,
    void* __restrict__ Cv, int M, int N, int K,
    const float* __restrict__ cost, const float* __restrict__ sint)
{
    constexpr int BK = 64;
    __shared__ u16 As[2][BM * BK];
    __shared__ u16 Bs[2][BN * BK];
    const int t = threadIdx.x;
    const int lane = t & 63, wid = t >> 6;
    const int wr = wid >> 1, wc = wid & 1;
    const int g = lane >> 4, cl = lane & 15;
    const size_t bm = (size_t)blockIdx.y * BM;
    const size_t bn = (size_t)blockIdx.x * BN;
    constexpr int MR = BM / 32, NR = BN / 32;
    constexpr int APW = BM * BK * 2 / 1024 / 4;   // 1KB rounds per wave (A)
    constexpr int BPW = BN * BK * 2 / 1024 / 4;

    auto stage = [&](int buf, int k0) {
#pragma unroll
        for (int i = 0; i < APW; ++i) {
            int rnd = wid * APW + i;
            int fb  = (rnd << 10) + (lane << 4);
            int row = fb >> 7;                    // 128 B per row (BK=64)
            int ke  = (fb & 127) >> 1;
            gload_lds16(A + (bm + row) * K + k0 + ke, (char*)As[buf] + (rnd << 10));
        }
#pragma unroll
        for (int i = 0; i < BPW; ++i) {
            int rnd = wid * BPW + i;
            int fb  = (rnd << 10) + (lane << 4);
            int row = fb >> 7;
            int ke  = (fb & 127) >> 1;
            gload_lds16(Bt + (bn + row) * K + k0 + ke, (char*)Bs[buf] + (rnd << 10));
        }
    };

    f32x4 acc[MR][NR] = {};
    stage(0, 0);
    int cur = 0;
    for (int k0 = 0; k0 < K; k0 += BK) {
        __syncthreads();   // drains vmcnt(0): buf[cur] staged; buf[cur^1] free
        if (k0 + BK < K) stage(cur ^ 1, k0 + BK);   // async, overlaps compute
#pragma unroll
        for (int ks = 0; ks < 2; ++ks) {
            s16x8 av[MR], bv[NR];
#pragma unroll
            for (int m = 0; m < MR; ++m)
                av[m] = *(const s16x8*)((const char*)As[cur] +
                        (wr*(BM/2) + m*16 + cl) * 128 + ks*64 + g*16);
#pragma unroll
            for (int n = 0; n < NR; ++n)
                bv[n] = *(const s16x8*)((const char*)Bs[cur] +
                        (wc*(BN/2) + n*16 + cl) * 128 + ks*64 + g*16);
#pragma unroll
            for (int m = 0; m < MR; ++m)
#pragma unroll
                for (int n = 0; n < NR; ++n)
                    acc[m][n] = __builtin_amdgcn_mfma_f32_16x16x32_bf16(
                        __builtin_bit_cast(bf16x8, av[m]),
                        __builtin_bit_cast(bf16x8, bv[n]), acc[m][n], 0, 0, 0);
        }
        cur ^= 1;
    }

    // epilogue: C layout col=lane&15, row=(lane>>4)*4+j (m89-verified)
    if constexpr (OMODE == 3) {
        const int band = ((int)(bn >> 6)) + wc;       // global 64-col band
        const bool pe = (band % 3) == 2;              // rope band (wave-uniform)
        u16* C = (u16*)Cv;
#pragma unroll
        for (int m = 0; m < MR; ++m) {
            const size_t rbase = bm + wr*(BM/2) + m*16 + g*4;
            if (pe) {
#pragma unroll
                for (int n = 0; n < 2; ++n) {
                    const int j = n*16 + cl;          // freq index [0,32)
                    const size_t colA = bn + wc*(BN/2) + n*16 + cl;
#pragma unroll
                    for (int jj = 0; jj < 4; ++jj) {
                        const size_t r = rbase + jj;
                        float co = cost[r*32 + j], sn = sint[r*32 + j];
                        float a = acc[m][n][jj], b = acc[m][n+2][jj];
                        C[r*N + colA]      = f2bf(a*co - b*sn);
                        C[r*N + colA + 32] = f2bf(b*co + a*sn);
                    }
                }
            } else {
#pragma unroll
                for (int n = 0; n < NR; ++n) {
                    const size_t col = bn + wc*(BN/2) + n*16 + cl;
#pragma unroll
                    for (int jj = 0; jj < 4; ++jj)
                        C[(rbase + jj)*N + col] = f2bf(acc[m][n][jj]);
                }
            }
        }
    } else {
#pragma unroll
        for (int m = 0; m < MR; ++m)
#pragma unroll
            for (int n = 0; n < NR; ++n) {
                size_t col = bn + wc*(BN/2) + n*16 + cl;
#pragma unroll
                for (int j = 0; j < 4; ++j) {
                    size_t row = bm + wr*(BM/2) + m*16 + g*4 + j;
                    if constexpr (OMODE == 0)
                        ((float*)Cv)[row * N + col] = acc[m][n][j];
                    else if constexpr (OMODE == 1)
                        ((u16*)Cv)[row * N + col] = f2bf(acc[m][n][j]);
                    else
                        ((u16*)Cv)[col * M + row] = f2bf(acc[m][n][j]);
                }
            }
    }
}

// =====================================================================
// Fused weight transpose+cast (5 weights): fp32 [K][N] -> bf16 [N][K].
// grid (96, 64, 5); per-z dims; out-of-range tiles exit early.
// =====================================================================
__global__ __launch_bounds__(256) void transpose_cast5(
    const float* __restrict__ w0, u16* __restrict__ o0,
    const float* __restrict__ w1, u16* __restrict__ o1,
    const float* __restrict__ w2, u16* __restrict__ o2,
    const float* __restrict__ w3, u16* __restrict__ o3,
    const float* __restrict__ w4, u16* __restrict__ o4)
{
    const int z = blockIdx.z;
    const float* in; u16* out; int K, N;
    if      (z == 0) { in = w0; out = o0; K = 2048; N = 1536; }
    else if (z == 1) { in = w1; out = o1; K = 2048; N = 512;  }
    else if (z == 2) { in = w2; out = o2; K = 1536; N = 3072; }
    else if (z == 3) { in = w3; out = o3; K = 512;  N = 3072; }
    else             { in = w4; out = o4; K = 512;  N = 2048; }
    const int bn = blockIdx.x * 32, bk = blockIdx.y * 32;
    if (bn >= N || bk >= K) return;

    __shared__ float tile[32][33];
    const int tx = threadIdx.x & 31, ty = threadIdx.x >> 5;
#pragma unroll
    for (int r = 0; r < 32; r += 8)
        tile[ty + r][tx] = in[(size_t)(bk + ty + r) * N + bn + tx];
    __syncthreads();
#pragma unroll
    for (int r = 0; r < 32; r += 8)
        out[(size_t)(bn + ty + r) * K + bk + tx] = f2bf(tile[tx][ty + r]);
}

__global__ __launch_bounds__(256) void transpose_cast(
    const float* __restrict__ in, u16* __restrict__ out, int K, int N)
{
    __shared__ float tile[32][33];
    const int bk = blockIdx.y * 32, bn = blockIdx.x * 32;
    const int tx = threadIdx.x & 31, ty = threadIdx.x >> 5;
#pragma unroll
    for (int r = 0; r < 32; r += 8)
        tile[ty + r][tx] = in[(size_t)(bk + ty + r) * N + bn + tx];
    __syncthreads();
#pragma unroll
    for (int r = 0; r < 32; r += 8)
        out[(size_t)(bn + ty + r) * K + bk + tx] = f2bf(tile[tx][ty + r]);
}

__global__ __launch_bounds__(256) void cast_f32_bf16(
    const float* __restrict__ in, u16* __restrict__ out, long n)
{
    long i = ((long)blockIdx.x * 256 + threadIdx.x) * 4;
    if (i >= n) return;
    f32x4 v = *(const f32x4*)(in + i);
    ushort4 q;
    q.x = f2bf(v[0]); q.y = f2bf(v[1]); q.z = f2bf(v[2]); q.w = f2bf(v[3]);
    *(ushort4*)(out + i) = q;
}

// =====================================================================
// RMSNorm: fp32 in -> bf16 out (one block per row)
// =====================================================================
__global__ __launch_bounds__(256) void rmsnorm_bf(
    const float* __restrict__ x, const float* __restrict__ w,
    u16* __restrict__ o, int N, float invN)
{
    const int row = blockIdx.x;
    const float* xr = x + (size_t)row * N;
    u16* orow = o + (size_t)row * N;
    const int t = threadIdx.x;
    float ss = 0.f;
    for (int i = t * 4; i < N; i += 1024) {
        f32x4 v = *(const f32x4*)&xr[i];
        ss += v[0]*v[0] + v[1]*v[1] + v[2]*v[2] + v[3]*v[3];
    }
#pragma unroll
    for (int off = 32; off > 0; off >>= 1) ss += __shfl_down(ss, off, 64);
    __shared__ float red[4];
    __shared__ float sinv;
    if ((t & 63) == 0) red[t >> 6] = ss;
    __syncthreads();
    if (t == 0) sinv = rsqrtf((red[0]+red[1]+red[2]+red[3]) * invN + 1e-5f);
    __syncthreads();
    const float si = sinv;
    for (int i = t * 4; i < N; i += 1024) {
        f32x4 v = *(const f32x4*)&xr[i];
        f32x4 wv = *(const f32x4*)&w[i];
        ushort4 q;
        q.x = f2bf(v[0]*wv[0]*si); q.y = f2bf(v[1]*wv[1]*si);
        q.z = f2bf(v[2]*wv[2]*si); q.w = f2bf(v[3]*wv[3]*si);
        *(ushort4*)&orow[i] = q;
    }
}

// RoPE cos/sin table: [S][32]
__global__ __launch_bounds__(256) void rope_table_k(
    float* __restrict__ cost, float* __restrict__ sint)
{
    int idx = blockIdx.x * 256 + threadIdx.x;     // S*32
    int tp = idx >> 5, j = idx & 31;
    float invf = powf(100000.0f, -(float)j * (1.0f / 32.0f));
    float fr = (float)tp * invf;
    cost[idx] = cosf(fr);
    sint[idx] = sinf(fr);
}

// =====================================================================
// Attention, fully-MFMA (as R3) + s_setprio around MFMA clusters.
// =====================================================================
__global__ __launch_bounds__(256) void attn_mfma(
    const u16* __restrict__ qg, const u16* __restrict__ kg,
    const u16* __restrict__ vtg, u16* __restrict__ og)
{
    __shared__ u16 Ks[64 * 192];       // 24KB, row 384B, swz (row&7)<<4
    __shared__ u16 VTs[128 * 64];      // 16KB, row 128B, swz (dv&7)<<4
    __shared__ u16 Ps[4][16 * 64];     // 8KB, per-wave, row 128B, swz (q&7)<<4

    const int t = threadIdx.x, lane = t & 63, wid = t >> 6;
    const int g = lane >> 4, cl = lane & 15;
    const int h = blockIdx.y;
    const int bx = blockIdx.x;
    const int qt = (bx & 1) ? (31 - (bx >> 1)) : (bx >> 1);  // causal balance
    const int qbase = qt * 64;
    const int wrow = wid * 16;

    // Q fragments (A-operand: row=lane&15, k=(lane>>4)*8+j)
    s16x8 qv[6];
    {
        const u16* qrow = qg + (size_t)(qbase + wrow + cl) * QCOLS + h * 192;
#pragma unroll
        for (int s = 0; s < 6; ++s)
            qv[s] = *(const s16x8*)(qrow + s * 32 + g * 8);
    }
    float mreg[4], lreg[4];
#pragma unroll
    for (int j = 0; j < 4; ++j) { mreg[j] = -1e30f; lreg[j] = 0.f; }

    f32x4 accO[8] = {};    // O[q=g*4+j][dv=nb*16+cl]
    char* pw = (char*)Ps[wid];

    for (int kt = 0; kt <= qt; ++kt) {
        const int kbase = kt * 64;
        __syncthreads();   // prev tile's Ks/VTs fully consumed
        // ---- stage K: 24 rounds of 1KB, 6 per wave, pre-swizzled src ----
        {
            const char* ksrc = (const char*)(kg + (size_t)kbase * QCOLS + h * 192);
#pragma unroll
            for (int i = 0; i < 6; ++i) {
                int rnd = wid * 6 + i;
                int fb  = (rnd << 10) + (lane << 4);
                int row = fb / 384;
                int cb  = fb - row * 384;
                gload_lds16(ksrc + (size_t)row * (QCOLS * 2)
                                 + (cb ^ ((row & 7) << 4)),
                            (char*)Ks + (rnd << 10));
            }
            // ---- stage VT: 16 rounds of 1KB, 4 per wave ----
            const char* vsrc = (const char*)(vtg + (size_t)(h * 128) * S_LEN + kbase);
#pragma unroll
            for (int i = 0; i < 4; ++i) {
                int rnd = wid * 4 + i;
                int fb  = (rnd << 10) + (lane << 4);
                int dv  = fb >> 7;
                int cb  = fb & 127;
                gload_lds16(vsrc + (size_t)dv * (S_LEN * 2)
                                 + (cb ^ ((dv & 7) << 4)),
                            (char*)VTs + (rnd << 10));
            }
        }
        __syncthreads();

        // ---- QK^T: S[16q][64kv] per wave ----
        f32x4 accS[4] = {};
        __builtin_amdgcn_s_setprio(1);
#pragma unroll
        for (int n = 0; n < 4; ++n) {
            const int kvrow = n * 16 + cl;
            const char* krow = (const char*)Ks + kvrow * 384;
            const int sw = (kvrow & 7) << 4;
#pragma unroll
            for (int s = 0; s < 6; ++s) {
                s16x8 kv8 = *(const s16x8*)(krow + ((s * 64 + g * 16) ^ sw));
                accS[n] = __builtin_amdgcn_mfma_f32_16x16x32_bf16(
                    __builtin_bit_cast(bf16x8, qv[s]),
                    __builtin_bit_cast(bf16x8, kv8), accS[n], 0, 0, 0);
            }
        }
        __builtin_amdgcn_s_setprio(0);

        // ---- mask + scale + online softmax (rows g*4+j, all lanes) ----
        float pm[4][4];   // [n][j]
        float cj[4];
#pragma unroll
        for (int j = 0; j < 4; ++j) {
            const int qrow = qbase + wrow + g * 4 + j;
            float mx = -1e30f;
#pragma unroll
            for (int n = 0; n < 4; ++n) {
                int kcol = kbase + n * 16 + cl;
                float s = accS[n][j] * ATT_SCALE;
                s = (kcol <= qrow) ? s : -1e30f;
                pm[n][j] = s;
                mx = fmaxf(mx, s);
            }
#pragma unroll
            for (int off = 1; off < 16; off <<= 1)
                mx = fmaxf(mx, __shfl_xor(mx, off, 64));
            float mnew = fmaxf(mreg[j], mx);
            float c = __expf(mreg[j] - mnew);
            float rs = 0.f;
#pragma unroll
            for (int n = 0; n < 4; ++n) {
                float p = __expf(pm[n][j] - mnew);
                pm[n][j] = p;
                rs += p;
            }
#pragma unroll
            for (int off = 1; off < 16; off <<= 1)
                rs += __shfl_xor(rs, off, 64);
            lreg[j] = lreg[j] * c + rs;
            mreg[j] = mnew;
            cj[j] = c;
        }

        // ---- write P (bf16) into per-wave LDS tile [q][kv], swizzled ----
#pragma unroll
        for (int n = 0; n < 4; ++n)
#pragma unroll
            for (int j = 0; j < 4; ++j) {
                int q = g * 4 + j;
                int byte = (q * 128 + (n * 16 + cl) * 2) ^ ((q & 7) << 4);
                *(u16*)(pw + byte) = f2bf(pm[n][j]);
            }

        // ---- rescale O, then PV via MFMA ----
#pragma unroll
        for (int nb = 0; nb < 8; ++nb)
#pragma unroll
            for (int j = 0; j < 4; ++j) accO[nb][j] *= cj[j];

        __builtin_amdgcn_s_setprio(1);
#pragma unroll
        for (int ks = 0; ks < 2; ++ks) {
            s16x8 pa = *(const s16x8*)(pw +
                ((cl * 128 + ks * 64 + g * 16) ^ ((cl & 7) << 4)));
#pragma unroll
            for (int nb = 0; nb < 8; ++nb) {
                s16x8 vb = *(const s16x8*)((const char*)VTs +
                    (((nb * 16 + cl) * 128 + ks * 64 + g * 16) ^ ((cl & 7) << 4)));
                accO[nb] = __builtin_amdgcn_mfma_f32_16x16x32_bf16(
                    __builtin_bit_cast(bf16x8, pa),
                    __builtin_bit_cast(bf16x8, vb), accO[nb], 0, 0, 0);
            }
        }
        __builtin_amdgcn_s_setprio(0);
    }

    // ---- epilogue: O /= l, store bf16 ----
#pragma unroll
    for (int j = 0; j < 4; ++j) {
        float inv = 1.f / lreg[j];
        u16* orow = og + (size_t)(qbase + wrow + g * 4 + j) * VCOLS + h * 128;
#pragma unroll
        for (int nb = 0; nb < 8; ++nb)
            orow[nb * 16 + cl] = f2bf(accO[nb][j] * inv);
    }
}

// =====================================================================
// Host launcher
// =====================================================================
extern "C" void kernel_launch(void* const* d_in, const int* in_sizes, int n_in,
                              void* d_out, int out_size, void* d_ws, size_t ws_size,
                              hipStream_t stream)
{
    const float* x         = (const float*)d_in[0];
    const float* wq_down   = (const float*)d_in[1];
    const float* q_norm_w  = (const float*)d_in[2];
    const float* wq_up     = (const float*)d_in[3];
    const float* wkv_down  = (const float*)d_in[4];
    const float* kv_norm_w = (const float*)d_in[5];
    const float* wk_up     = (const float*)d_in[6];
    const float* wv_up     = (const float*)d_in[7];
    const float* wo        = (const float*)d_in[8];
    float* out = (float*)d_out;
    char* ws = (char*)d_ws;

    u16*  WQD_T  = (u16*)(ws + 0);            // 6,291,456 B
    u16*  WKVD_T = (u16*)(ws + 6291456);      // 2,097,152
    u16*  WQU_T  = (u16*)(ws + 8388608);      // 9,437,184
    u16*  WKU_T  = (u16*)(ws + 17825792);     // 3,145,728
    u16*  WVU_T  = (u16*)(ws + 20971520);     // 2,097,152
    u16*  XBF    = (u16*)(ws + 23068672);     // 8,388,608
    float* QLAT  = (float*)(ws + 31457280);   // 12,582,912
    float* KVLAT = (float*)(ws + 44040192);   // 4,194,304
    u16*  QLATB  = (u16*)(ws + 48234496);     // 6,291,456
    u16*  KVLATB = (u16*)(ws + 54525952);     // 2,097,152
    u16*  QBUF   = (u16*)(ws + 56623104);     // 12,582,912
    u16*  KBUF   = (u16*)(ws + 69206016);     // 12,582,912
    float* COST  = (float*)(ws + 81788928);   // 262,144
    float* SINT  = (float*)(ws + 82051072);   // 262,144
    // aliases over dead regions:
    u16*  WO_T   = (u16*)(ws + 0);            // over WQD_T+WKVD_T (dead after down-proj)
    u16*  VTBUF  = (u16*)(ws + 31457280);     // over QLAT (dead after rmsnorm)
    u16*  ATTNO  = (u16*)(ws + 23068672);     // over XBF (dead after down-proj)

    // weight prep (one fused dispatch for the 5 early weights) + x cast + table
    transpose_cast5<<<dim3(96, 64, 5), 256, 0, stream>>>(
        wq_down, WQD_T, wkv_down, WKVD_T, wq_up, WQU_T, wk_up, WKU_T, wv_up, WVU_T);
    cast_f32_bf16<<<4096, 256, 0, stream>>>(x, XBF, (long)S_LEN * 2048);
    rope_table_k<<<256, 256, 0, stream>>>(COST, SINT);

    // down-projections (fp32 out for RMSNorm)
    gemm_bf16<128,128,0><<<dim3(12, 16), 256, 0, stream>>>(
        XBF, WQD_T,  QLAT,  2048, 1536, 2048, nullptr, nullptr);
    gemm_bf16< 64, 64,0><<<dim3( 8, 32), 256, 0, stream>>>(
        XBF, WKVD_T, KVLAT, 2048,  512, 2048, nullptr, nullptr);
    rmsnorm_bf<<<2048, 256, 0, stream>>>(QLAT,  q_norm_w,  QLATB,  1536, 1.f/1536.f);
    rmsnorm_bf<<<2048, 256, 0, stream>>>(KVLAT, kv_norm_w, KVLATB, 512,  1.f/512.f);
    transpose_cast<<<dim3(64, 64), 256, 0, stream>>>(wo, WO_T, 2048, 2048);

    // up-projections; RoPE fused into q/k epilogues (OMODE 3)
    gemm_bf16<128,128,3><<<dim3(24, 16), 256, 0, stream>>>(
        QLATB,  WQU_T, QBUF,  2048, 3072, 1536, COST, SINT);
    gemm_bf16<128,128,3><<<dim3(24, 16), 256, 0, stream>>>(
        KVLATB, WKU_T, KBUF,  2048, 3072, 512,  COST, SINT);
    gemm_bf16<128,128,2><<<dim3(16, 16), 256, 0, stream>>>(
        KVLATB, WVU_T, VTBUF, 2048, 2048, 512,  nullptr, nullptr);

    // attention + output projection
    attn_mfma<<<dim3(32, 16), 256, 0, stream>>>(QBUF, KBUF, VTBUF, ATTNO);
    gemm_bf16<128,128,0><<<dim3(16, 16), 256, 0, stream>>>(
        ATTNO, WO_T, out, 2048, 2048, 2048, nullptr, nullptr);
}